// Round 3
// baseline (185.889 us; speedup 1.0000x reference)
//
#include <hip/hip_runtime.h>

typedef __bf16 bf16;
typedef __bf16 bf16x4 __attribute__((ext_vector_type(4)));
typedef __bf16 bf16x8 __attribute__((ext_vector_type(8)));
typedef float f32x4 __attribute__((ext_vector_type(4)));

// B_Nq = B_Ns = 16, C = 512, P = 1024, TAU*C = 256. I/O fp32; GEMMs bf16 MFMA.

#define GLL16(g, l)                                                             \
    __builtin_amdgcn_global_load_lds((const __attribute__((address_space(1))) void*)(g), \
                                     (__attribute__((address_space(3))) void*)(l), 16, 0, 0)

__device__ inline float wave_reduce_sum(float v) {
#pragma unroll
    for (int m = 32; m >= 1; m >>= 1) v += __shfl_xor(v, m, 64);
    return v;
}
__device__ inline float wave_reduce_max(float v) {
#pragma unroll
    for (int m = 32; m >= 1; m >>= 1) v = fmaxf(v, __shfl_xor(v, m, 64));
    return v;
}

// K0: fs_mean (fp32+bf16) + transpose. f_q is no longer touched here (gemm1
// converts on the fly from fp32). grid (32 p-tiles, 16 c-tiles), block 256.
__global__ void k_prep(const float* __restrict__ fs, float* __restrict__ fsm32,
                       bf16* __restrict__ fsm16, bf16* __restrict__ fsmT) {
    __shared__ bf16 tile[32][33];
    int bx = blockIdx.x, by = blockIdx.y;
    int p0 = bx * 32, c0 = by * 32;
    int t = threadIdx.x;
    int cy = t >> 3, px = (t & 7) * 4;
    size_t off = (size_t)(c0 + cy) * 1024 + p0 + px;
    float4 s = {0.f, 0.f, 0.f, 0.f};
#pragma unroll
    for (int b = 0; b < 16; ++b) {
        float4 v = *(const float4*)(fs + (size_t)b * 524288 + off);
        s.x += v.x; s.y += v.y; s.z += v.z; s.w += v.w;
    }
    s.x *= (1.f / 16.f); s.y *= (1.f / 16.f); s.z *= (1.f / 16.f); s.w *= (1.f / 16.f);
    *(float4*)(fsm32 + off) = s;
    bf16x4 h4 = {(bf16)s.x, (bf16)s.y, (bf16)s.z, (bf16)s.w};
    *(bf16x4*)(fsm16 + off) = h4;
    tile[cy][px] = h4[0];
    tile[cy][px + 1] = h4[1];
    tile[cy][px + 2] = h4[2];
    tile[cy][px + 3] = h4[3];
    __syncthreads();
    int tx = t & 31, ty = t >> 5;
#pragma unroll
    for (int i = 0; i < 4; ++i)
        fsmT[(size_t)(p0 + ty + 8 * i) * 512 + c0 + tx] = tile[tx][ty + 8 * i];
}

// K1: rm[c] = rowmean(fs_mean[c,:]); u[c] = wsq[c]*wsk[c]*rm[c]/256
__global__ void k_u(const float* __restrict__ fsm32, const float* __restrict__ wsq,
                    const float* __restrict__ wsk, float* __restrict__ u,
                    float* __restrict__ rm) {
    int c = blockIdx.x;
    int t = threadIdx.x;
    float s = 0.f;
#pragma unroll
    for (int j = 0; j < 4; ++j) s += fsm32[(size_t)c * 1024 + t + 256 * j];
    s = wave_reduce_sum(s);
    __shared__ float red[4];
    int w = t >> 6, lane = t & 63;
    if (lane == 0) red[w] = s;
    __syncthreads();
    if (t == 0) {
        float rmv = (red[0] + red[1] + red[2] + red[3]) * (1.f / 1024.f);
        rm[c] = rmv;
        u[c] = wsq[c] * wsk[c] * rmv * (1.f / 256.f);
    }
}

// K2: G[b,c,d] = sum_p bf16(f_q[b,c,p])*fsm16[d,p] — 64(c)x128(d) tile, BK=64.
// A staged as RAW FP32 via global_load_lds (cvt to bf16 at fragment load).
// Counted-vmcnt 2-deep pipeline: raw s_barrier + vmcnt(8), never 0 in-loop —
// loads for step s+2 stay in flight across step s+1's barriers.
// XOR-swizzle: A fp32 (16 chunks/row, mask row&15), B bf16 (8 chunks/row, mask row&7),
// applied on the pre-swizzled global source (global_load_lds writes linearly).
// grid (4 dt, 8 ct, 16 b) = 512 blocks; LDS 64 KB -> 2 blocks/CU.
__global__ void k_gemm1(const float* __restrict__ A, const bf16* __restrict__ B,
                        float* __restrict__ G) {
    __shared__ alignas(16) float Asf[2][64 * 64];
    __shared__ alignas(16) bf16 Bs[2][128 * 64];
    const int dt = blockIdx.x, ct = blockIdx.y, b = blockIdx.z;
    const int t = threadIdx.x, w = t >> 6, lane = t & 63;
    const int quad = lane >> 4, r15 = lane & 15;
    const int wr = w & 1, wc = w >> 1;
    const float* Abase = A + ((size_t)(b * 512 + ct * 64)) * 1024;
    const bf16* Bbase = B + ((size_t)(dt * 128)) * 1024;
    f32x4 acc[2][4] = {};
    auto STAGE = [&](int buf, int k0) {
#pragma unroll
        for (int i = 0; i < 4; ++i) {  // A: fp32 64 rows x 64 k
            int row = i * 16 + (t >> 4);
            int gchunk = (t & 15) ^ (row & 15);
            GLL16(Abase + (size_t)row * 1024 + k0 + gchunk * 4, &Asf[buf][(i * 256 + t) * 4]);
        }
#pragma unroll
        for (int i = 0; i < 4; ++i) {  // B: bf16 128 rows x 64 k
            int row = i * 32 + (t >> 3);
            int gchunk = (t & 7) ^ (row & 7);
            GLL16(Bbase + (size_t)row * 1024 + k0 + gchunk * 8, &Bs[buf][(i * 256 + t) * 8]);
        }
    };
    STAGE(0, 0);
    STAGE(1, 64);
    for (int s = 0; s < 16; ++s) {
        if (s < 15) asm volatile("s_waitcnt vmcnt(8)" ::: "memory");
        else        asm volatile("s_waitcnt vmcnt(0)" ::: "memory");
        __builtin_amdgcn_s_barrier();
        const int cur = s & 1;
#pragma unroll
        for (int ks = 0; ks < 2; ++ks) {
            bf16x8 af[2], bfr[4];
            const int c8 = ks * 4 + quad;
#pragma unroll
            for (int mi = 0; mi < 2; ++mi) {
                int R = wr * 32 + mi * 16 + r15;
                f32x4 a0 = *(const f32x4*)(&Asf[cur][R * 64 + (((2 * c8) ^ (R & 15)) * 4)]);
                f32x4 a1 = *(const f32x4*)(&Asf[cur][R * 64 + (((2 * c8 + 1) ^ (R & 15)) * 4)]);
                af[mi] = bf16x8{(bf16)a0[0], (bf16)a0[1], (bf16)a0[2], (bf16)a0[3],
                                (bf16)a1[0], (bf16)a1[1], (bf16)a1[2], (bf16)a1[3]};
            }
#pragma unroll
            for (int j = 0; j < 4; ++j) {
                int R = wc * 64 + j * 16 + r15;
                bfr[j] = *(const bf16x8*)(&Bs[cur][R * 64 + ((c8 ^ (R & 7)) * 8)]);
            }
#pragma unroll
            for (int mi = 0; mi < 2; ++mi)
#pragma unroll
                for (int j = 0; j < 4; ++j)
                    acc[mi][j] = __builtin_amdgcn_mfma_f32_16x16x32_bf16(af[mi], bfr[j], acc[mi][j], 0, 0, 0);
        }
        __builtin_amdgcn_s_barrier();
        if (s + 2 < 16) STAGE(cur, (s + 2) * 64);
    }
#pragma unroll
    for (int mi = 0; mi < 2; ++mi) {
        float* g = G + ((size_t)(b * 512 + ct * 64 + wr * 32 + mi * 16 + quad * 4)) * 512 +
                   dt * 128 + wc * 64 + r15;
#pragma unroll
        for (int j = 0; j < 4; ++j)
#pragma unroll
            for (int ii = 0; ii < 4; ++ii)
                g[(size_t)ii * 512 + j * 16] = acc[mi][j][ii];
    }
}

// K3: row softmax of G*wq[c]*wk[d]/P -> Acw (folds wv); r[b,c] = sum_d Acw*rm[d].
// Also zero-inits alog+blog (32K contiguous floats) for the atomic accumulators.
__global__ void k_softmax_ac(const float* __restrict__ G, const float* __restrict__ wq,
                             const float* __restrict__ wk, const float* __restrict__ wv,
                             const float* __restrict__ rm, bf16* __restrict__ Acw,
                             float* __restrict__ r, float* __restrict__ zbuf) {
    if (blockIdx.x < 128) zbuf[blockIdx.x * 256 + threadIdx.x] = 0.f;
    int row = blockIdx.x * 4 + (threadIdx.x >> 6);  // b*512 + c
    int lane = threadIdx.x & 63;
    int c = row & 511;
    const float* g = G + (size_t)row * 512;
    float sc = wq[c] * (1.f / 1024.f);
    float v[8];
    float mx = -3.4e38f;
#pragma unroll
    for (int j = 0; j < 8; ++j) {
        int d = lane + 64 * j;
        v[j] = g[d] * sc * wk[d];
        mx = fmaxf(mx, v[j]);
    }
    mx = wave_reduce_max(mx);
    float sum = 0.f;
#pragma unroll
    for (int j = 0; j < 8; ++j) {
        v[j] = __expf(v[j] - mx);
        sum += v[j];
    }
    sum = wave_reduce_sum(sum);
    float inv = 1.f / sum;
    bf16* o = Acw + (size_t)row * 512;
    float rsum = 0.f;
#pragma unroll
    for (int j = 0; j < 8; ++j) {
        int d = lane + 64 * j;
        float aw = v[j] * inv * wv[d];
        o[d] = (bf16)aw;
        rsum += aw * rm[d];
    }
    rsum = wave_reduce_sum(rsum);
    if (lane == 0) r[row] = rsum;
}

// K5: out[b,c,p] = fq + lam*CP; CP[b,c,p] = sum_d Acw[b,c,d]*fsmT[p,d].
// Counted-vmcnt 2-deep pipeline (6 loads/STAGE -> vmcnt(6)). Epilogue adds
// alog[b,p] += sum_{c in tile} u[c]*CP[b,c,p] (shfl reduce + atomicAdd).
// grid (8 pt, 8 ct, 16 b) = 1024 blocks; LDS 48 KB -> 3 blocks/CU.
__global__ void k_gemm2(const bf16* __restrict__ A, const bf16* __restrict__ B,
                        const float* __restrict__ fq, const float* __restrict__ lamp,
                        const float* __restrict__ u, float* __restrict__ out,
                        float* __restrict__ alog) {
    __shared__ alignas(16) bf16 As[2][64 * 64];
    __shared__ alignas(16) bf16 Bs[2][128 * 64];
    const int pt = blockIdx.x, ct = blockIdx.y, b = blockIdx.z;
    const int t = threadIdx.x, w = t >> 6, lane = t & 63;
    const int quad = lane >> 4, r15 = lane & 15;
    const int wr = w & 1, wc = w >> 1;
    const bf16* Abase = A + ((size_t)(b * 512 + ct * 64)) * 512;
    const bf16* Bbase = B + ((size_t)(pt * 128)) * 512;
    f32x4 acc[2][4] = {};
    auto STAGE = [&](int buf, int k0) {
#pragma unroll
        for (int i = 0; i < 2; ++i) {  // A: bf16 64 rows x 64 k
            int row = i * 32 + (t >> 3);
            int gchunk = (t & 7) ^ (row & 7);
            GLL16(Abase + (size_t)row * 512 + k0 + gchunk * 8, &As[buf][(i * 256 + t) * 8]);
        }
#pragma unroll
        for (int i = 0; i < 4; ++i) {  // B: bf16 128 rows x 64 k
            int row = i * 32 + (t >> 3);
            int gchunk = (t & 7) ^ (row & 7);
            GLL16(Bbase + (size_t)row * 512 + k0 + gchunk * 8, &Bs[buf][(i * 256 + t) * 8]);
        }
    };
    STAGE(0, 0);
    STAGE(1, 64);
    for (int s = 0; s < 8; ++s) {
        if (s < 7) asm volatile("s_waitcnt vmcnt(6)" ::: "memory");
        else       asm volatile("s_waitcnt vmcnt(0)" ::: "memory");
        __builtin_amdgcn_s_barrier();
        const int cur = s & 1;
#pragma unroll
        for (int ks = 0; ks < 2; ++ks) {
            bf16x8 af[2], bfr[4];
            const int c8 = ks * 4 + quad;
#pragma unroll
            for (int mi = 0; mi < 2; ++mi) {
                int R = wr * 32 + mi * 16 + r15;
                af[mi] = *(const bf16x8*)(&As[cur][R * 64 + ((c8 ^ (R & 7)) * 8)]);
            }
#pragma unroll
            for (int j = 0; j < 4; ++j) {
                int R = wc * 64 + j * 16 + r15;
                bfr[j] = *(const bf16x8*)(&Bs[cur][R * 64 + ((c8 ^ (R & 7)) * 8)]);
            }
#pragma unroll
            for (int mi = 0; mi < 2; ++mi)
#pragma unroll
                for (int j = 0; j < 4; ++j)
                    acc[mi][j] = __builtin_amdgcn_mfma_f32_16x16x32_bf16(af[mi], bfr[j], acc[mi][j], 0, 0, 0);
        }
        __builtin_amdgcn_s_barrier();
        if (s + 2 < 8) STAGE(cur, (s + 2) * 64);
    }
    float lam = lamp[0];
#pragma unroll
    for (int mi = 0; mi < 2; ++mi) {
        size_t rowbase = (size_t)(b * 512 + ct * 64 + wr * 32 + mi * 16 + quad * 4);
#pragma unroll
        for (int j = 0; j < 4; ++j)
#pragma unroll
            for (int ii = 0; ii < 4; ++ii) {
                size_t idx = (rowbase + ii) * 1024 + pt * 128 + wc * 64 + j * 16 + r15;
                out[idx] = fq[idx] + lam * acc[mi][j][ii];
            }
    }
    // u-weighted row reduction -> alog partial
    float uv[2][4];
#pragma unroll
    for (int mi = 0; mi < 2; ++mi)
#pragma unroll
        for (int ii = 0; ii < 4; ++ii)
            uv[mi][ii] = u[ct * 64 + wr * 32 + mi * 16 + quad * 4 + ii];
#pragma unroll
    for (int j = 0; j < 4; ++j) {
        float pv = 0.f;
#pragma unroll
        for (int mi = 0; mi < 2; ++mi)
#pragma unroll
            for (int ii = 0; ii < 4; ++ii)
                pv += uv[mi][ii] * acc[mi][j][ii];
        pv += __shfl_xor(pv, 16, 64);
        pv += __shfl_xor(pv, 32, 64);
        if (lane < 16)
            atomicAdd(alog + (size_t)b * 1024 + pt * 128 + wc * 64 + j * 16 + r15, pv);
    }
}

// K6: blog[b,q] += sum_{c chunk} r[b,c]*wsq[c]*wsk[c]/256 * fsm32[c,q]
// grid (4 pq, 16 b, 4 c-chunks), atomicAdd into zero-inited blog.
__global__ void k_blog(const float* __restrict__ r, const float* __restrict__ wsq,
                       const float* __restrict__ wsk, const float* __restrict__ fsm32,
                       float* __restrict__ blog) {
    int pq = blockIdx.x * 256 + threadIdx.x;
    int b = blockIdx.y;
    int c0 = blockIdx.z * 128;
    const float* rb = r + b * 512;
    float s0 = 0.f, s1 = 0.f, s2 = 0.f, s3 = 0.f;
#pragma unroll 4
    for (int c = c0; c < c0 + 128; c += 4) {
        s0 += rb[c] * wsq[c] * wsk[c] * fsm32[(size_t)c * 1024 + pq];
        s1 += rb[c + 1] * wsq[c + 1] * wsk[c + 1] * fsm32[(size_t)(c + 1) * 1024 + pq];
        s2 += rb[c + 2] * wsq[c + 2] * wsk[c + 2] * fsm32[(size_t)(c + 2) * 1024 + pq];
        s3 += rb[c + 3] * wsq[c + 3] * wsk[c + 3] * fsm32[(size_t)(c + 3) * 1024 + pq];
    }
    atomicAdd(&blog[(size_t)b * 1024 + pq], ((s0 + s1) + (s2 + s3)) * (1.f / 256.f));
}

// K7: z<16: alpha softmax -> out; z>=16: beta softmax -> ws
__global__ void k_softmax_rows(const float* __restrict__ alog, const float* __restrict__ blog,
                               float* __restrict__ alpha_out, float* __restrict__ beta) {
    int z = blockIdx.x;
    int t = threadIdx.x;
    int w = t >> 6, lane = t & 63;
    const float* src = (z < 16) ? (alog + (size_t)z * 1024) : (blog + (size_t)(z - 16) * 1024);
    float v[4];
    float mx = -3.4e38f;
#pragma unroll
    for (int j = 0; j < 4; ++j) {
        v[j] = src[t + 256 * j];
        mx = fmaxf(mx, v[j]);
    }
    __shared__ float red[4];
    float wm = wave_reduce_max(mx);
    if (lane == 0) red[w] = wm;
    __syncthreads();
    mx = fmaxf(fmaxf(red[0], red[1]), fmaxf(red[2], red[3]));
    float s = 0.f;
#pragma unroll
    for (int j = 0; j < 4; ++j) {
        v[j] = __expf(v[j] - mx);
        s += v[j];
    }
    __syncthreads();
    float ws_ = wave_reduce_sum(s);
    if (lane == 0) red[w] = ws_;
    __syncthreads();
    s = red[0] + red[1] + red[2] + red[3];
    float inv = 1.f / s;
    if (z < 16) {
#pragma unroll
        for (int j = 0; j < 4; ++j) alpha_out[(size_t)z * 1024 + t + 256 * j] = v[j] * inv;
    } else {
#pragma unroll
        for (int j = 0; j < 4; ++j) beta[(size_t)(z - 16) * 1024 + t + 256 * j] = v[j] * inv;
    }
}

// K8: beta_mean broadcast
__global__ void k_betamean(const float* __restrict__ beta, float* __restrict__ out) {
    int q = blockIdx.x * 256 + threadIdx.x;
    float s = 0.f;
#pragma unroll
    for (int b = 0; b < 16; ++b) s += beta[b * 1024 + q];
    float val = s * (1.f / 16.f);
#pragma unroll
    for (int si = 0; si < 16; ++si) out[(size_t)si * 1024 + q] = val;
}

extern "C" void kernel_launch(void* const* d_in, const int* in_sizes, int n_in,
                              void* d_out, int out_size, void* d_ws, size_t ws_size,
                              hipStream_t stream) {
    const float* f_q = (const float*)d_in[0];
    const float* f_s = (const float*)d_in[1];
    const float* w_cca_q = (const float*)d_in[2];
    const float* w_cca_k = (const float*)d_in[3];
    const float* w_cca_v = (const float*)d_in[4];
    const float* w_sca_q = (const float*)d_in[5];
    const float* w_sca_k = (const float*)d_in[6];
    const float* lamp = (const float*)d_in[7];

    char* ws = (char*)d_ws;
    float* fsm32 = (float*)(ws + 0);             //  2 MB   [512,1024]
    bf16* fsm16 = (bf16*)(ws + 2097152);         //  1 MB
    bf16* fsmT = (bf16*)(ws + 3145728);          //  1 MB   [1024,512]
    float* G = (float*)(ws + 4194304);           // 16 MB   [16,512,512]
    bf16* Acw = (bf16*)(ws + 20971520);          //  8 MB   [16,512,512]
    float* rm = (float*)(ws + 46137344);         //  2 KB
    float* u = (float*)(ws + 46139392);          //  2 KB
    float* r = (float*)(ws + 46141440);          // 32 KB   [16,512]
    float* alog = (float*)(ws + 46239744);       // 64 KB  (contiguous with blog)
    float* blog = (float*)(ws + 46305280);       // 64 KB
    float* beta = (float*)(ws + 46370816);       // 64 KB

    float* out_fq = (float*)d_out;
    float* out_alpha = out_fq + 8388608;
    float* out_bmean = out_fq + 8404992;

    k_prep<<<dim3(32, 16), 256, 0, stream>>>(f_s, fsm32, fsm16, fsmT);
    k_u<<<512, 256, 0, stream>>>(fsm32, w_sca_q, w_sca_k, u, rm);
    k_gemm1<<<dim3(4, 8, 16), 256, 0, stream>>>(f_q, fsm16, G);
    k_softmax_ac<<<2048, 256, 0, stream>>>(G, w_cca_q, w_cca_k, w_cca_v, rm, Acw, r, alog);
    k_gemm2<<<dim3(8, 8, 16), 256, 0, stream>>>(Acw, fsmT, f_q, lamp, u, out_fq, alog);
    k_blog<<<dim3(4, 16, 4), 256, 0, stream>>>(r, w_sca_q, w_sca_k, fsm32, blog);
    k_softmax_rows<<<32, 256, 0, stream>>>(alog, blog, out_alpha, beta);
    k_betamean<<<4, 256, 0, stream>>>(beta, out_bmean);
}

// Round 4
// 172.115 us; speedup vs baseline: 1.0800x; 1.0800x over previous
//
#include <hip/hip_runtime.h>

typedef __bf16 bf16;
typedef __bf16 bf16x4 __attribute__((ext_vector_type(4)));
typedef __bf16 bf16x8 __attribute__((ext_vector_type(8)));
typedef float f32x4 __attribute__((ext_vector_type(4)));

// B_Nq = B_Ns = 16, C = 512, P = 1024, TAU*C = 256. I/O fp32; GEMMs bf16 MFMA.
// 5-dispatch structure: prep -> gemm1(+rm/u) -> softmax_ac(+zero) -> gemm2(+alog+blog) -> softmax_rows(+bmean).

#define GLL16(g, l)                                                             \
    __builtin_amdgcn_global_load_lds((const __attribute__((address_space(1))) void*)(g), \
                                     (__attribute__((address_space(3))) void*)(l), 16, 0, 0)

__device__ inline float wave_reduce_sum(float v) {
#pragma unroll
    for (int m = 32; m >= 1; m >>= 1) v += __shfl_xor(v, m, 64);
    return v;
}
__device__ inline float wave_reduce_max(float v) {
#pragma unroll
    for (int m = 32; m >= 1; m >>= 1) v = fmaxf(v, __shfl_xor(v, m, 64));
    return v;
}

// K0: fs_mean (fp32+bf16+transpose), f_q->bf16, and per-p-tile row partials rmpart[32][512].
// grid (32 p-tiles, 16 c-tiles), block 256.
__global__ void k_prep(const float* __restrict__ fs, const float* __restrict__ fq,
                       float* __restrict__ fsm32, bf16* __restrict__ fsm16,
                       bf16* __restrict__ fsmT, bf16* __restrict__ fq16,
                       float* __restrict__ rmpart) {
    __shared__ bf16 tile[32][33];
    int bx = blockIdx.x, by = blockIdx.y;
    int p0 = bx * 32, c0 = by * 32;
    int t = threadIdx.x;
    int cy = t >> 3, px = (t & 7) * 4;
    size_t off = (size_t)(c0 + cy) * 1024 + p0 + px;
    float4 s = {0.f, 0.f, 0.f, 0.f};
#pragma unroll
    for (int b = 0; b < 16; ++b) {
        float4 v = *(const float4*)(fs + (size_t)b * 524288 + off);
        s.x += v.x; s.y += v.y; s.z += v.z; s.w += v.w;
    }
    s.x *= (1.f / 16.f); s.y *= (1.f / 16.f); s.z *= (1.f / 16.f); s.w *= (1.f / 16.f);
    *(float4*)(fsm32 + off) = s;
    bf16x4 h4 = {(bf16)s.x, (bf16)s.y, (bf16)s.z, (bf16)s.w};
    *(bf16x4*)(fsm16 + off) = h4;
    tile[cy][px] = h4[0];
    tile[cy][px + 1] = h4[1];
    tile[cy][px + 2] = h4[2];
    tile[cy][px + 3] = h4[3];
    // row partial over this p-tile (shfl across the 8 threads covering the row)
    float rp = s.x + s.y + s.z + s.w;
    rp += __shfl_xor(rp, 1, 64);
    rp += __shfl_xor(rp, 2, 64);
    rp += __shfl_xor(rp, 4, 64);
    if ((t & 7) == 0) rmpart[bx * 512 + c0 + cy] = rp;
    __syncthreads();
    int tx = t & 31, ty = t >> 5;
#pragma unroll
    for (int i = 0; i < 4; ++i)
        fsmT[(size_t)(p0 + ty + 8 * i) * 512 + c0 + tx] = tile[tx][ty + 8 * i];
    // f_q fp32 -> bf16, 16384 floats per block
    int blk = by * 32 + bx;
    const float4* f4 = (const float4*)fq;
#pragma unroll
    for (int i = 0; i < 16; ++i) {
        int idx = blk * 4096 + i * 256 + t;  // float4 index
        float4 v = f4[idx];
        bf16x4 q4 = {(bf16)v.x, (bf16)v.y, (bf16)v.z, (bf16)v.w};
        *(bf16x4*)(fq16 + (size_t)idx * 4) = q4;
    }
}

// K2: G[b,c,d] = sum_p fq16[b,c,p]*fsm16[d,p] — 64(c)x128(d) tile, BK=64.
// Counted-vmcnt 2-deep pipeline (6 loads/STAGE). 48 KB LDS -> 3 blocks/CU.
// Blocks with (dt==0,b==0) also finalize rm[c], u[c] from rmpart.
// grid (4 dt, 8 ct, 16 b) = 512 blocks.
__global__ void k_gemm1(const bf16* __restrict__ A, const bf16* __restrict__ B,
                        const float* __restrict__ rmpart, const float* __restrict__ wsq,
                        const float* __restrict__ wsk, float* __restrict__ rm,
                        float* __restrict__ u, float* __restrict__ G) {
    __shared__ alignas(16) bf16 As[2][64 * 64];
    __shared__ alignas(16) bf16 Bs[2][128 * 64];
    const int dt = blockIdx.x, ct = blockIdx.y, b = blockIdx.z;
    const int t = threadIdx.x, w = t >> 6, lane = t & 63;
    const int quad = lane >> 4, r15 = lane & 15;
    const int wr = w & 1, wc = w >> 1;
    // rm/u finalize (8 blocks only; runs before the GEMM loads so vmcnt stays conservative-safe)
    if (dt == 0 && b == 0) {
        int c = ct * 64 + (t >> 2);
        float sum = 0.f;
#pragma unroll
        for (int j = 0; j < 8; ++j) sum += rmpart[((t & 3) * 8 + j) * 512 + c];
        sum += __shfl_xor(sum, 1, 64);
        sum += __shfl_xor(sum, 2, 64);
        if ((t & 3) == 0) {
            float rmv = sum * (1.f / 1024.f);
            rm[c] = rmv;
            u[c] = wsq[c] * wsk[c] * rmv * (1.f / 256.f);
        }
    }
    const bf16* Abase = A + ((size_t)(b * 512 + ct * 64)) * 1024;
    const bf16* Bbase = B + ((size_t)(dt * 128)) * 1024;
    f32x4 acc[2][4] = {};
    auto STAGE = [&](int buf, int k0) {
#pragma unroll
        for (int i = 0; i < 2; ++i) {  // A: 64 rows x 64 k
            int row = i * 32 + (t >> 3);
            int gchunk = (t & 7) ^ (row & 7);
            GLL16(Abase + (size_t)row * 1024 + k0 + gchunk * 8, &As[buf][(i * 256 + t) * 8]);
        }
#pragma unroll
        for (int i = 0; i < 4; ++i) {  // B: 128 rows x 64 k
            int row = i * 32 + (t >> 3);
            int gchunk = (t & 7) ^ (row & 7);
            GLL16(Bbase + (size_t)row * 1024 + k0 + gchunk * 8, &Bs[buf][(i * 256 + t) * 8]);
        }
    };
    STAGE(0, 0);
    STAGE(1, 64);
    for (int s = 0; s < 16; ++s) {
        if (s < 15) asm volatile("s_waitcnt vmcnt(6)" ::: "memory");
        else        asm volatile("s_waitcnt vmcnt(0)" ::: "memory");
        __builtin_amdgcn_s_barrier();
        const int cur = s & 1;
#pragma unroll
        for (int ks = 0; ks < 2; ++ks) {
            bf16x8 af[2], bfr[4];
            const int c8 = ks * 4 + quad;
#pragma unroll
            for (int mi = 0; mi < 2; ++mi) {
                int R = wr * 32 + mi * 16 + r15;
                af[mi] = *(const bf16x8*)(&As[cur][R * 64 + ((c8 ^ (R & 7)) * 8)]);
            }
#pragma unroll
            for (int j = 0; j < 4; ++j) {
                int R = wc * 64 + j * 16 + r15;
                bfr[j] = *(const bf16x8*)(&Bs[cur][R * 64 + ((c8 ^ (R & 7)) * 8)]);
            }
#pragma unroll
            for (int mi = 0; mi < 2; ++mi)
#pragma unroll
                for (int j = 0; j < 4; ++j)
                    acc[mi][j] = __builtin_amdgcn_mfma_f32_16x16x32_bf16(af[mi], bfr[j], acc[mi][j], 0, 0, 0);
        }
        __builtin_amdgcn_s_barrier();
        if (s + 2 < 16) STAGE(cur, (s + 2) * 64);
    }
#pragma unroll
    for (int mi = 0; mi < 2; ++mi) {
        float* g = G + ((size_t)(b * 512 + ct * 64 + wr * 32 + mi * 16 + quad * 4)) * 512 +
                   dt * 128 + wc * 64 + r15;
#pragma unroll
        for (int j = 0; j < 4; ++j)
#pragma unroll
            for (int ii = 0; ii < 4; ++ii)
                g[(size_t)ii * 512 + j * 16] = acc[mi][j][ii];
    }
}

// K3: row softmax of G*wq[c]*wk[d]/P -> Acw (folds wv); r[b,c] = sum_d Acw*rm[d].
// Zero-inits alog+blog+bmean+cnt (34048 contiguous floats) for the atomic accumulators.
__global__ void k_softmax_ac(const float* __restrict__ G, const float* __restrict__ wq,
                             const float* __restrict__ wk, const float* __restrict__ wv,
                             const float* __restrict__ rm, bf16* __restrict__ Acw,
                             float* __restrict__ r, float* __restrict__ zbuf) {
    if (blockIdx.x < 133) zbuf[blockIdx.x * 256 + threadIdx.x] = 0.f;
    int row = blockIdx.x * 4 + (threadIdx.x >> 6);  // b*512 + c
    int lane = threadIdx.x & 63;
    int c = row & 511;
    const float* g = G + (size_t)row * 512;
    float sc = wq[c] * (1.f / 1024.f);
    float v[8];
    float mx = -3.4e38f;
#pragma unroll
    for (int j = 0; j < 8; ++j) {
        int d = lane + 64 * j;
        v[j] = g[d] * sc * wk[d];
        mx = fmaxf(mx, v[j]);
    }
    mx = wave_reduce_max(mx);
    float sum = 0.f;
#pragma unroll
    for (int j = 0; j < 8; ++j) {
        v[j] = __expf(v[j] - mx);
        sum += v[j];
    }
    sum = wave_reduce_sum(sum);
    float inv = 1.f / sum;
    bf16* o = Acw + (size_t)row * 512;
    float rsum = 0.f;
#pragma unroll
    for (int j = 0; j < 8; ++j) {
        int d = lane + 64 * j;
        float aw = v[j] * inv * wv[d];
        o[d] = (bf16)aw;
        rsum += aw * rm[d];
    }
    rsum = wave_reduce_sum(rsum);
    if (lane == 0) r[row] = rsum;
}

// K5: out[b,c,p] = fq + lam*CP; CP[b,c,p] = sum_d Acw[b,c,d]*fsmT[p,d].
// Counted-vmcnt 2-deep pipeline. Epilogues: alog atomic (all blocks),
// blog atomic (ct==0 blocks: 128 blocks cover [b]x[q-range]).
// grid (8 pt, 8 ct, 16 b) = 1024 blocks; ~50 KB LDS -> 3 blocks/CU.
__global__ void k_gemm2(const bf16* __restrict__ A, const bf16* __restrict__ B,
                        const float* __restrict__ fq, const float* __restrict__ lamp,
                        const float* __restrict__ u, const float* __restrict__ r,
                        const float* __restrict__ wsq, const float* __restrict__ wsk,
                        const float* __restrict__ fsm32, float* __restrict__ out,
                        float* __restrict__ alog, float* __restrict__ blog) {
    __shared__ alignas(16) bf16 As[2][64 * 64];
    __shared__ alignas(16) bf16 Bs[2][128 * 64];
    const int pt = blockIdx.x, ct = blockIdx.y, b = blockIdx.z;
    const int t = threadIdx.x, w = t >> 6, lane = t & 63;
    const int quad = lane >> 4, r15 = lane & 15;
    const int wr = w & 1, wc = w >> 1;
    const bf16* Abase = A + ((size_t)(b * 512 + ct * 64)) * 512;
    const bf16* Bbase = B + ((size_t)(pt * 128)) * 512;
    f32x4 acc[2][4] = {};
    auto STAGE = [&](int buf, int k0) {
#pragma unroll
        for (int i = 0; i < 2; ++i) {
            int row = i * 32 + (t >> 3);
            int gchunk = (t & 7) ^ (row & 7);
            GLL16(Abase + (size_t)row * 512 + k0 + gchunk * 8, &As[buf][(i * 256 + t) * 8]);
        }
#pragma unroll
        for (int i = 0; i < 4; ++i) {
            int row = i * 32 + (t >> 3);
            int gchunk = (t & 7) ^ (row & 7);
            GLL16(Bbase + (size_t)row * 512 + k0 + gchunk * 8, &Bs[buf][(i * 256 + t) * 8]);
        }
    };
    STAGE(0, 0);
    STAGE(1, 64);
    for (int s = 0; s < 8; ++s) {
        if (s < 7) asm volatile("s_waitcnt vmcnt(6)" ::: "memory");
        else       asm volatile("s_waitcnt vmcnt(0)" ::: "memory");
        __builtin_amdgcn_s_barrier();
        const int cur = s & 1;
#pragma unroll
        for (int ks = 0; ks < 2; ++ks) {
            bf16x8 af[2], bfr[4];
            const int c8 = ks * 4 + quad;
#pragma unroll
            for (int mi = 0; mi < 2; ++mi) {
                int R = wr * 32 + mi * 16 + r15;
                af[mi] = *(const bf16x8*)(&As[cur][R * 64 + ((c8 ^ (R & 7)) * 8)]);
            }
#pragma unroll
            for (int j = 0; j < 4; ++j) {
                int R = wc * 64 + j * 16 + r15;
                bfr[j] = *(const bf16x8*)(&Bs[cur][R * 64 + ((c8 ^ (R & 7)) * 8)]);
            }
#pragma unroll
            for (int mi = 0; mi < 2; ++mi)
#pragma unroll
                for (int j = 0; j < 4; ++j)
                    acc[mi][j] = __builtin_amdgcn_mfma_f32_16x16x32_bf16(af[mi], bfr[j], acc[mi][j], 0, 0, 0);
        }
        __builtin_amdgcn_s_barrier();
        if (s + 2 < 8) STAGE(cur, (s + 2) * 64);
    }
    float lam = lamp[0];
#pragma unroll
    for (int mi = 0; mi < 2; ++mi) {
        size_t rowbase = (size_t)(b * 512 + ct * 64 + wr * 32 + mi * 16 + quad * 4);
#pragma unroll
        for (int j = 0; j < 4; ++j)
#pragma unroll
            for (int ii = 0; ii < 4; ++ii) {
                size_t idx = (rowbase + ii) * 1024 + pt * 128 + wc * 64 + j * 16 + r15;
                out[idx] = fq[idx] + lam * acc[mi][j][ii];
            }
    }
    // u-weighted row reduction -> alog partial
    float uv[2][4];
#pragma unroll
    for (int mi = 0; mi < 2; ++mi)
#pragma unroll
        for (int ii = 0; ii < 4; ++ii)
            uv[mi][ii] = u[ct * 64 + wr * 32 + mi * 16 + quad * 4 + ii];
#pragma unroll
    for (int j = 0; j < 4; ++j) {
        float pv = 0.f;
#pragma unroll
        for (int mi = 0; mi < 2; ++mi)
#pragma unroll
            for (int ii = 0; ii < 4; ++ii)
                pv += uv[mi][ii] * acc[mi][j][ii];
        pv += __shfl_xor(pv, 16, 64);
        pv += __shfl_xor(pv, 32, 64);
        if (lane < 16)
            atomicAdd(alog + (size_t)b * 1024 + pt * 128 + wc * 64 + j * 16 + r15, pv);
    }
    // blog epilogue: 128 blocks (ct==0) compute blog[b, pt*128..+128)
    if (ct == 0) {
        __shared__ float coef[512];
        coef[t] = r[b * 512 + t] * wsq[t] * wsk[t] * (1.f / 256.f);
        coef[t + 256] = r[b * 512 + t + 256] * wsq[t + 256] * wsk[t + 256] * (1.f / 256.f);
        __syncthreads();
        int q = pt * 128 + (t & 127);
        int ch = t >> 7;
        const float* f = fsm32 + (size_t)(ch * 256) * 1024 + q;
        const float* cf = coef + ch * 256;
        float s0 = 0.f, s1 = 0.f, s2 = 0.f, s3 = 0.f;
#pragma unroll 4
        for (int ci = 0; ci < 256; ci += 4) {
            s0 += cf[ci] * f[(size_t)ci * 1024];
            s1 += cf[ci + 1] * f[(size_t)(ci + 1) * 1024];
            s2 += cf[ci + 2] * f[(size_t)(ci + 2) * 1024];
            s3 += cf[ci + 3] * f[(size_t)(ci + 3) * 1024];
        }
        atomicAdd(&blog[(size_t)b * 1024 + q], (s0 + s1) + (s2 + s3));
    }
}

// K7: z<16: alpha softmax -> out; z>=16: beta softmax -> atomic bmean;
// last-finishing beta block broadcasts bmean to the 16 output rows.
__global__ void k_softmax_rows(const float* __restrict__ alog, const float* __restrict__ blog,
                               float* __restrict__ alpha_out, float* __restrict__ bmean,
                               int* __restrict__ cnt, float* __restrict__ out_bmean) {
    int z = blockIdx.x;
    int t = threadIdx.x;
    int w = t >> 6, lane = t & 63;
    const float* src = (z < 16) ? (alog + (size_t)z * 1024) : (blog + (size_t)(z - 16) * 1024);
    float v[4];
    float mx = -3.4e38f;
#pragma unroll
    for (int j = 0; j < 4; ++j) {
        v[j] = src[t + 256 * j];
        mx = fmaxf(mx, v[j]);
    }
    __shared__ float red[4];
    float wm = wave_reduce_max(mx);
    if (lane == 0) red[w] = wm;
    __syncthreads();
    mx = fmaxf(fmaxf(red[0], red[1]), fmaxf(red[2], red[3]));
    float s = 0.f;
#pragma unroll
    for (int j = 0; j < 4; ++j) {
        v[j] = __expf(v[j] - mx);
        s += v[j];
    }
    __syncthreads();
    float ws_ = wave_reduce_sum(s);
    if (lane == 0) red[w] = ws_;
    __syncthreads();
    s = red[0] + red[1] + red[2] + red[3];
    float inv = 1.f / s;
    if (z < 16) {
#pragma unroll
        for (int j = 0; j < 4; ++j) alpha_out[(size_t)z * 1024 + t + 256 * j] = v[j] * inv;
    } else {
        float inv16 = inv * (1.f / 16.f);
#pragma unroll
        for (int j = 0; j < 4; ++j) atomicAdd(&bmean[t + 256 * j], v[j] * inv16);
        __threadfence();
        __syncthreads();
        __shared__ int lastflag;
        if (t == 0) lastflag = (atomicAdd(cnt, 1) == 15) ? 1 : 0;
        __syncthreads();
        if (lastflag) {
            __threadfence();
#pragma unroll
            for (int j = 0; j < 4; ++j) {
                int q = t + 256 * j;
                float val = __hip_atomic_load(&bmean[q], __ATOMIC_ACQUIRE, __HIP_MEMORY_SCOPE_AGENT);
#pragma unroll
                for (int si = 0; si < 16; ++si) out_bmean[(size_t)si * 1024 + q] = val;
            }
        }
    }
}

extern "C" void kernel_launch(void* const* d_in, const int* in_sizes, int n_in,
                              void* d_out, int out_size, void* d_ws, size_t ws_size,
                              hipStream_t stream) {
    const float* f_q = (const float*)d_in[0];
    const float* f_s = (const float*)d_in[1];
    const float* w_cca_q = (const float*)d_in[2];
    const float* w_cca_k = (const float*)d_in[3];
    const float* w_cca_v = (const float*)d_in[4];
    const float* w_sca_q = (const float*)d_in[5];
    const float* w_sca_k = (const float*)d_in[6];
    const float* lamp = (const float*)d_in[7];

    char* ws = (char*)d_ws;
    float* fsm32 = (float*)(ws + 0);             //  2 MB   [512,1024]
    bf16* fsm16 = (bf16*)(ws + 2097152);         //  1 MB
    bf16* fsmT = (bf16*)(ws + 3145728);          //  1 MB   [1024,512]
    float* G = (float*)(ws + 4194304);           // 16 MB   [16,512,512]
    bf16* Acw = (bf16*)(ws + 20971520);          //  8 MB   [16,512,512]
    bf16* fq16 = (bf16*)(ws + 29360128);         // 16.8 MB [16,512,1024]
    float* rmpart = (float*)(ws + 46137344);     // 64 KB   [32,512]
    float* rm = (float*)(ws + 46202880);         //  2 KB
    float* u = (float*)(ws + 46204928);          //  2 KB
    float* r = (float*)(ws + 46206976);          // 32 KB   [16,512]
    float* alog = (float*)(ws + 46239744);       // 64 KB  -- zbuf start (alog,blog,bmean,cnt contiguous)
    float* blog = (float*)(ws + 46305280);       // 64 KB
    float* bmean = (float*)(ws + 46370816);      //  4 KB
    int* cnt = (int*)(ws + 46374912);            //  1 KB

    float* out_fq = (float*)d_out;
    float* out_alpha = out_fq + 8388608;
    float* out_bmean = out_fq + 8404992;

    k_prep<<<dim3(32, 16), 256, 0, stream>>>(f_s, f_q, fsm32, fsm16, fsmT, fq16, rmpart);
    k_gemm1<<<dim3(4, 8, 16), 256, 0, stream>>>(fq16, fsm16, rmpart, w_sca_q, w_sca_k, rm, u, G);
    k_softmax_ac<<<2048, 256, 0, stream>>>(G, w_cca_q, w_cca_k, w_cca_v, rm, Acw, r, alog);
    k_gemm2<<<dim3(8, 8, 16), 256, 0, stream>>>(Acw, fsmT, f_q, lamp, u, r, w_sca_q, w_sca_k,
                                                fsm32, out_fq, alog, blog);
    k_softmax_rows<<<32, 256, 0, stream>>>(alog, blog, out_alpha, bmean, cnt, out_bmean);
}